// Round 6
// baseline (100.293 us; speedup 1.0000x reference)
//
#include <hip/hip_runtime.h>
#include <hip/hip_bf16.h>
#include <hip/hip_cooperative_groups.h>

namespace cg = cooperative_groups;

// Problem constants (fixed by setup_inputs): B=4, S=8192, D=1024, E=64, top_k=1
#define NB 4
#define NS 8192
#define ND 1024
#define NE 64
#define NM (NB * NS)          // 32768 tokens
#define CAPACITY 640

#define BM 64                 // tokens per block == chunk size
#define BK 64                 // K-tile
#define NKT (ND / BK)         // 16 K-tiles
#define NBLK (NM / BM)        // 512 blocks (2 per CU -> cooperative-resident)
#define CPB (NS / BM)         // 128 chunks per batch

typedef short short8 __attribute__((ext_vector_type(8)));
typedef unsigned short ushort8 __attribute__((ext_vector_type(8)));
typedef float f32x4 __attribute__((ext_vector_type(4)));

// LDS swizzle: flat short-index within a [64 rows][64 shorts] tile.
// XOR bits 3-5 of the column with (row&7): conflict-free b128 column reads.
__device__ __forceinline__ int swz(int row, int colshorts) {
    return row * 64 + (colshorts ^ ((row & 7) << 3));
}

// ---------------------------------------------------------------------------
// K0: split W (fp32 [E][D]) into bf16 hi/lo planes (RNE both levels).
// ---------------------------------------------------------------------------
__global__ __launch_bounds__(256) void w_conv(const float* __restrict__ W,
                                              unsigned short* __restrict__ Wh,
                                              unsigned short* __restrict__ Wl)
{
    const int i = (blockIdx.x * 256 + threadIdx.x) * 4;
    float4 v = *(const float4*)(W + i);
    float f[4] = {v.x, v.y, v.z, v.w};
    ushort4 h, l;
    unsigned short* hp = &h.x;
    unsigned short* lp = &l.x;
#pragma unroll
    for (int c = 0; c < 4; ++c) {
        __hip_bfloat16 hb = __float2bfloat16(f[c]);
        float r = f[c] - __bfloat162float(hb);
        __hip_bfloat16 lb = __float2bfloat16(r);
        hp[c] = __builtin_bit_cast(unsigned short, hb);
        lp[c] = __builtin_bit_cast(unsigned short, lb);
    }
    *(ushort4*)(Wh + i) = h;
    *(ushort4*)(Wl + i) = l;
}

// ---------------------------------------------------------------------------
// K1 (cooperative, does everything else):
// Phase 1: LDS-tiled bf16x3-split MFMA GEMM (proven r5 structure) + fused
//   softmax-top1; logits staged in LDS then written dense (float4); per-chunk
//   hist written to global. argmax idx / prob kept in LDS (block == chunk).
// grid.sync()
// Phase 2: per-block prefix-base from hist (4-wave strided sum), ordered
//   capacity rank (wave 0, lane = expert), then DENSE float4 writes of
//   e_out / p_out (replaces zero-fill + sparse scatter).
// C/D layout (verified m89/m91): col = lane&15 (expert), row = (lane>>4)*4+reg.
// ---------------------------------------------------------------------------
__global__ __launch_bounds__(256, 2) void k1_mfma(const float* __restrict__ x,
                                                  const unsigned short* __restrict__ Wh,
                                                  const unsigned short* __restrict__ Wl,
                                                  float* __restrict__ logits,
                                                  float* __restrict__ e_out,
                                                  float* __restrict__ p_out,
                                                  int* __restrict__ hist)
{
    __shared__ char sbuf[16384];      // xs_h(8K)+xs_l(8K); reused as sLog (4096 f32)
    __shared__ short whs[64 * 64];
    __shared__ short wls[64 * 64];
    __shared__ int lh[NE];
    __shared__ int sMi[BM];
    __shared__ float sPr[BM];
    __shared__ int sAd[BM];
    __shared__ int pp[4][NE];

    short* xs_h = (short*)sbuf;
    short* xs_l = (short*)(sbuf + 8192);
    float* sLog = (float*)sbuf;

    const int tid = threadIdx.x;
    const int lane = tid & 63;
    const int wv = tid >> 6;
    const int lr = lane & 15;
    const int kq = lane >> 4;
    const int tok0 = blockIdx.x * BM;

    if (tid < NE) lh[tid] = 0;

    // x staging coords: row = tid>>2 (0..63), col group = (tid&3)*16
    const int xrow = tid >> 2;
    const int xcol = (tid & 3) * 16;
    const float* xsrc = x + (size_t)(tok0 + xrow) * ND + xcol;

    // W staging coords: per plane-instr i in {0,1}: e = (tid>>3)+i*32, col=(tid&7)*8
    const int we0 = tid >> 3;
    const int wcol = (tid & 7) * 8;

    f32x4 acc[4];
#pragma unroll
    for (int j = 0; j < 4; ++j) acc[j] = (f32x4){0.f, 0.f, 0.f, 0.f};

    // prefetch x tile 0
    float4 px[4], px2[4];
#pragma unroll
    for (int c = 0; c < 4; ++c) px[c] = *(const float4*)(xsrc + c * 4);

    for (int kt = 0; kt < NKT; ++kt) {
        const int k0 = kt * BK;
        if (kt > 0) __syncthreads();   // all waves done reading previous tile

        // ---- stage W planes (pure copy from pre-split, swizzled ds_write)
#pragma unroll
        for (int i = 0; i < 2; ++i) {
            const int e = we0 + i * 32;
            const size_t gs = (size_t)e * ND + k0 + wcol;
            ushort8 vh = *(const ushort8*)(Wh + gs);
            ushort8 vl = *(const ushort8*)(Wl + gs);
            *(ushort8*)&whs[swz(e, wcol)] = vh;
            *(ushort8*)&wls[swz(e, wcol)] = vl;
        }

        // ---- stage x: trunc-split px -> hi/lo, swizzled ds_write (8 B each)
#pragma unroll
        for (int c = 0; c < 4; ++c) {
            float f[4] = {px[c].x, px[c].y, px[c].z, px[c].w};
            ushort4 h4, l4;
            unsigned short* hp = &h4.x;
            unsigned short* lp = &l4.x;
#pragma unroll
            for (int e = 0; e < 4; ++e) {
                unsigned int u = __builtin_bit_cast(unsigned int, f[e]);
                hp[e] = (unsigned short)(u >> 16);
                float fhi = __builtin_bit_cast(float, u & 0xFFFF0000u);
                lp[e] = (unsigned short)(__builtin_bit_cast(unsigned int, f[e] - fhi) >> 16);
            }
            const int si = swz(xrow, xcol + c * 4);
            *(ushort4*)&xs_h[si] = h4;
            *(ushort4*)&xs_l[si] = l4;
        }

        // ---- prefetch next x tile (in flight during the MFMA phase)
        if (kt + 1 < NKT) {
#pragma unroll
            for (int c = 0; c < 4; ++c)
                px2[c] = *(const float4*)(xsrc + (k0 + BK) + c * 4);
        }

        __syncthreads();   // tile ready

        // ---- fragments + MFMA
#pragma unroll
        for (int kk = 0; kk < 2; ++kk) {
            const int col = kk * 32 + kq * 8;
            const int arow = wv * 16 + lr;
            short8 ah = *(const short8*)&xs_h[swz(arow, col)];
            short8 al = *(const short8*)&xs_l[swz(arow, col)];
#pragma unroll
            for (int j = 0; j < 4; ++j) {
                const int erow = j * 16 + lr;
                short8 bh = *(const short8*)&whs[swz(erow, col)];
                short8 bl = *(const short8*)&wls[swz(erow, col)];
                acc[j] = __builtin_amdgcn_mfma_f32_16x16x32_bf16(ah, bh, acc[j], 0, 0, 0);
                acc[j] = __builtin_amdgcn_mfma_f32_16x16x32_bf16(ah, bl, acc[j], 0, 0, 0);
                acc[j] = __builtin_amdgcn_mfma_f32_16x16x32_bf16(al, bh, acc[j], 0, 0, 0);
            }
        }

#pragma unroll
        for (int c = 0; c < 4; ++c) px[c] = px2[c];
    }

    __syncthreads();   // xs tiles dead; sLog may now overwrite them

    // ---- fused epilogue: per-token softmax top-1 (each wave: its 16 tokens)
#pragma unroll
    for (int r = 0; r < 4; ++r) {
        const int tl = wv * 16 + kq * 4 + r;   // token local to block
        float val[4];
#pragma unroll
        for (int j = 0; j < 4; ++j) val[j] = acc[j][r];

        // local argmax over j (ascending j + strict > keeps lowest expert)
        float m = val[0];
        int mi = lr;
#pragma unroll
        for (int j = 1; j < 4; ++j) {
            if (val[j] > m) { m = val[j]; mi = j * 16 + lr; }
        }
        // butterfly across the 16 lanes of this fragment-row group
#pragma unroll
        for (int off = 1; off < 16; off <<= 1) {
            float m2 = __shfl_xor(m, off);
            int mi2 = __shfl_xor(mi, off);
            if (m2 > m || (m2 == m && mi2 < mi)) { m = m2; mi = mi2; }
        }
        // softmax denominator
        float s = 0.0f;
#pragma unroll
        for (int j = 0; j < 4; ++j) s += __expf(val[j] - m);
#pragma unroll
        for (int off = 1; off < 16; off <<= 1) s += __shfl_xor(s, off);

        // stage logits in LDS for dense write
#pragma unroll
        for (int j = 0; j < 4; ++j) sLog[tl * NE + j * 16 + lr] = val[j];
        if (lr == 0) {
            sMi[tl] = mi;
            sPr[tl] = 1.0f / s;
            atomicAdd(&lh[mi], 1);
        }
    }
    __syncthreads();

    // dense logits write: 4 x 4 KB contiguous float4 stores
    const size_t g0 = (size_t)tok0 * NE;
#pragma unroll
    for (int i = 0; i < 4; ++i) {
        const int fl = i * 1024 + tid * 4;
        *(float4*)&logits[g0 + fl] = *(const float4*)&sLog[fl];
    }
    if (tid < NE) hist[blockIdx.x * NE + tid] = lh[tid];

    // ================= phase 2: capacity + dense e/p writes =================
    cg::this_grid().sync();

    const int b = blockIdx.x / CPB;
    const int cin = blockIdx.x % CPB;

    // 4-wave strided partial sums of earlier chunks' hist (order-independent)
    {
        int run = 0;
        const int* hrow = hist + (size_t)b * CPB * NE + lane;
        for (int c = wv; c < cin; c += 4) run += hrow[c * NE];
        pp[wv][lane] = run;
    }
    __syncthreads();

    if (wv == 0) {
        int run = pp[0][lane] + pp[1][lane] + pp[2][lane] + pp[3][lane];
        // ordered capacity rank: lane = expert, serial over the chunk's tokens
        for (int j = 0; j < BM; ++j) {
            if (sMi[j] == lane) { ++run; sAd[j] = (run <= CAPACITY) ? 1 : 0; }
        }
    }
    __syncthreads();

    // dense e/p writes
#pragma unroll
    for (int i = 0; i < 4; ++i) {
        const int fl = i * 1024 + tid * 4;
        const int t = fl >> 6;
        const int e0 = fl & 63;
        const int mi = sMi[t];
        const float pr = sPr[t];
        const int ad = sAd[t];
        float4 ev, pv;
        float* evp = &ev.x;
        float* pvp = &pv.x;
#pragma unroll
        for (int c = 0; c < 4; ++c) {
            const bool hit = (mi == e0 + c) && ad;
            evp[c] = hit ? 1.0f : 0.0f;
            pvp[c] = hit ? pr : 0.0f;
        }
        *(float4*)&e_out[g0 + fl] = ev;
        *(float4*)&p_out[g0 + fl] = pv;
    }
}

// ---------------------------------------------------------------------------
extern "C" void kernel_launch(void* const* d_in, const int* in_sizes, int n_in,
                              void* d_out, int out_size, void* d_ws, size_t ws_size,
                              hipStream_t stream)
{
    const float* x = (const float*)d_in[0];   // [B,S,D] fp32
    const float* W = (const float*)d_in[1];   // [E,D] fp32
    // d_in[2] = top_k (==1), ignored

    float* out = (float*)d_out;
    float* e_out = out;                          // expert_indices as 0.0/1.0
    float* p_out = out + (size_t)NM * NE;        // router_probs
    float* logits = out + 2 * (size_t)NM * NE;   // logits

    char* ws = (char*)d_ws;
    int* hist = (int*)ws;                                        // 512*64*4 = 128 KB
    unsigned short* Wh = (unsigned short*)(ws + 131072);         // 128 KB
    unsigned short* Wl = (unsigned short*)(ws + 262144);         // 128 KB

    w_conv<<<NE * ND / (256 * 4), 256, 0, stream>>>(W, Wh, Wl);

    const float* xa = x;
    const unsigned short* wha = Wh;
    const unsigned short* wla = Wl;
    float* la = logits;
    float* ea = e_out;
    float* pa = p_out;
    int* ha = hist;
    void* kargs[] = {(void*)&xa, (void*)&wha, (void*)&wla, (void*)&la,
                     (void*)&ea, (void*)&pa, (void*)&ha};
    hipLaunchCooperativeKernel((const void*)k1_mfma, dim3(NBLK), dim3(256),
                               kargs, 0, stream);
}

// Round 7
// 53.865 us; speedup vs baseline: 1.8619x; 1.8619x over previous
//
#include <hip/hip_runtime.h>
#include <hip/hip_bf16.h>

// Problem constants (fixed by setup_inputs): B=4, S=8192, D=1024, E=64, top_k=1
#define NB 4
#define NS 8192
#define ND 1024
#define NE 64
#define NM (NB * NS)          // 32768 tokens
#define CAPACITY 640

#define BM 32                 // tokens per k1 block (= hist chunk size)
#define BK 64                 // K-tile
#define NKT (ND / BK)         // 16 K-tiles
#define NBLK (NM / BM)        // 1024 blocks -> ~6 resident/CU (LDS-limited)
#define C32PB (NS / BM)       // 256 32-chunks per batch

#define OCH 64                // tokens per output block
#define NOB (NM / OCH)        // 512 output blocks

typedef short short8 __attribute__((ext_vector_type(8)));
typedef unsigned short ushort8 __attribute__((ext_vector_type(8)));
typedef float f32x4 __attribute__((ext_vector_type(4)));

// LDS swizzle: flat short-index within a [rows][64 shorts] tile.
// XOR bits 3-5 of the column with (row&7): conflict-free b128 column reads.
__device__ __forceinline__ int swz(int row, int colshorts) {
    return row * 64 + (colshorts ^ ((row & 7) << 3));
}

// ---------------------------------------------------------------------------
// K0: split W (fp32 [E][D]) into bf16 hi/lo planes (RNE both levels).
// ---------------------------------------------------------------------------
__global__ __launch_bounds__(256) void w_conv(const float* __restrict__ W,
                                              unsigned short* __restrict__ Wh,
                                              unsigned short* __restrict__ Wl)
{
    const int i = (blockIdx.x * 256 + threadIdx.x) * 4;
    float4 v = *(const float4*)(W + i);
    float f[4] = {v.x, v.y, v.z, v.w};
    ushort4 h, l;
    unsigned short* hp = &h.x;
    unsigned short* lp = &l.x;
#pragma unroll
    for (int c = 0; c < 4; ++c) {
        __hip_bfloat16 hb = __float2bfloat16(f[c]);
        float r = f[c] - __bfloat162float(hb);
        __hip_bfloat16 lb = __float2bfloat16(r);
        hp[c] = __builtin_bit_cast(unsigned short, hb);
        lp[c] = __builtin_bit_cast(unsigned short, lb);
    }
    *(ushort4*)(Wh + i) = h;
    *(ushort4*)(Wl + i) = l;
}

// ---------------------------------------------------------------------------
// K1: LDS-tiled bf16x3-split MFMA GEMM + fused softmax-top1.
// 128 threads = 2 waves; BM=32 tokens x 64 experts, 16 K-tiles of 64.
// Wave w owns tokens [tok0 + w*16, +16) over FULL K (per-token MFMA sequence
// bitwise-identical to the r5/r6 passing kernels). ~25 KB LDS -> 6 blocks/CU.
// Writes: dense logits (via LDS re-stage), idx/prob/hist to ws. NO e/p here.
// C/D layout (verified m89/m91): col = lane&15 (expert), row = (lane>>4)*4+reg.
// ---------------------------------------------------------------------------
__global__ __launch_bounds__(128) void k1_mfma(const float* __restrict__ x,
                                               const unsigned short* __restrict__ Wh,
                                               const unsigned short* __restrict__ Wl,
                                               float* __restrict__ logits,
                                               int* __restrict__ idx_ws,
                                               float* __restrict__ prob_ws,
                                               int* __restrict__ hist)
{
    __shared__ char sbuf[8192];       // xs_h(4K)+xs_l(4K); reused as sLog (2048 f32)
    __shared__ short whs[64 * 64];    // 8 KB
    __shared__ short wls[64 * 64];    // 8 KB
    __shared__ int lh[NE];

    short* xs_h = (short*)sbuf;
    short* xs_l = (short*)(sbuf + 4096);
    float* sLog = (float*)sbuf;

    const int tid = threadIdx.x;
    const int lane = tid & 63;
    const int wv = tid >> 6;          // 0..1
    const int lr = lane & 15;
    const int kq = lane >> 4;
    const int tok0 = blockIdx.x * BM;

    if (tid < NE) lh[tid] = 0;

    // x staging coords: row = tid>>2 (0..31), col group = (tid&3)*16
    const int xrow = tid >> 2;
    const int xcol = (tid & 3) * 16;
    const float* xsrc = x + (size_t)(tok0 + xrow) * ND + xcol;

    // W staging coords: per instr i in 0..3: e = (tid>>3)+i*16, col=(tid&7)*8
    const int we0 = tid >> 3;         // 0..15
    const int wcol = (tid & 7) * 8;

    f32x4 acc[4];
#pragma unroll
    for (int j = 0; j < 4; ++j) acc[j] = (f32x4){0.f, 0.f, 0.f, 0.f};

    // prefetch x tile 0
    float4 px[4], px2[4];
#pragma unroll
    for (int c = 0; c < 4; ++c) px[c] = *(const float4*)(xsrc + c * 4);

    for (int kt = 0; kt < NKT; ++kt) {
        const int k0 = kt * BK;
        if (kt > 0) __syncthreads();   // all waves done reading previous tile

        // ---- stage W planes (pure copy from pre-split, swizzled ds_write)
#pragma unroll
        for (int i = 0; i < 4; ++i) {
            const int e = we0 + i * 16;
            const size_t gs = (size_t)e * ND + k0 + wcol;
            ushort8 vh = *(const ushort8*)(Wh + gs);
            ushort8 vl = *(const ushort8*)(Wl + gs);
            *(ushort8*)&whs[swz(e, wcol)] = vh;
            *(ushort8*)&wls[swz(e, wcol)] = vl;
        }

        // ---- stage x: trunc-split px -> hi/lo, swizzled ds_write (8 B each)
#pragma unroll
        for (int c = 0; c < 4; ++c) {
            float f[4] = {px[c].x, px[c].y, px[c].z, px[c].w};
            ushort4 h4, l4;
            unsigned short* hp = &h4.x;
            unsigned short* lp = &l4.x;
#pragma unroll
            for (int e = 0; e < 4; ++e) {
                unsigned int u = __builtin_bit_cast(unsigned int, f[e]);
                hp[e] = (unsigned short)(u >> 16);
                float fhi = __builtin_bit_cast(float, u & 0xFFFF0000u);
                lp[e] = (unsigned short)(__builtin_bit_cast(unsigned int, f[e] - fhi) >> 16);
            }
            const int si = swz(xrow, xcol + c * 4);
            *(ushort4*)&xs_h[si] = h4;
            *(ushort4*)&xs_l[si] = l4;
        }

        // ---- prefetch next x tile (in flight during the MFMA phase)
        if (kt + 1 < NKT) {
#pragma unroll
            for (int c = 0; c < 4; ++c)
                px2[c] = *(const float4*)(xsrc + (k0 + BK) + c * 4);
        }

        __syncthreads();   // tile ready

        // ---- fragments + MFMA
#pragma unroll
        for (int kk = 0; kk < 2; ++kk) {
            const int col = kk * 32 + kq * 8;
            const int arow = wv * 16 + lr;
            short8 ah = *(const short8*)&xs_h[swz(arow, col)];
            short8 al = *(const short8*)&xs_l[swz(arow, col)];
#pragma unroll
            for (int j = 0; j < 4; ++j) {
                const int erow = j * 16 + lr;
                short8 bh = *(const short8*)&whs[swz(erow, col)];
                short8 bl = *(const short8*)&wls[swz(erow, col)];
                acc[j] = __builtin_amdgcn_mfma_f32_16x16x32_bf16(ah, bh, acc[j], 0, 0, 0);
                acc[j] = __builtin_amdgcn_mfma_f32_16x16x32_bf16(ah, bl, acc[j], 0, 0, 0);
                acc[j] = __builtin_amdgcn_mfma_f32_16x16x32_bf16(al, bh, acc[j], 0, 0, 0);
            }
        }

#pragma unroll
        for (int c = 0; c < 4; ++c) px[c] = px2[c];
    }

    __syncthreads();   // xs tiles dead; sLog may now overwrite them

    // ---- fused epilogue: per-token softmax top-1 (each wave: its 16 tokens)
#pragma unroll
    for (int r = 0; r < 4; ++r) {
        const int tl = wv * 16 + kq * 4 + r;   // token local to block (0..31)
        float val[4];
#pragma unroll
        for (int j = 0; j < 4; ++j) val[j] = acc[j][r];

        // local argmax over j (ascending j + strict > keeps lowest expert)
        float m = val[0];
        int mi = lr;
#pragma unroll
        for (int j = 1; j < 4; ++j) {
            if (val[j] > m) { m = val[j]; mi = j * 16 + lr; }
        }
        // butterfly across the 16 lanes of this fragment-row group
#pragma unroll
        for (int off = 1; off < 16; off <<= 1) {
            float m2 = __shfl_xor(m, off);
            int mi2 = __shfl_xor(mi, off);
            if (m2 > m || (m2 == m && mi2 < mi)) { m = m2; mi = mi2; }
        }
        // softmax denominator
        float s = 0.0f;
#pragma unroll
        for (int j = 0; j < 4; ++j) s += __expf(val[j] - m);
#pragma unroll
        for (int off = 1; off < 16; off <<= 1) s += __shfl_xor(s, off);

        // stage logits in LDS for dense write
#pragma unroll
        for (int j = 0; j < 4; ++j) sLog[tl * NE + j * 16 + lr] = val[j];
        if (lr == 0) {
            idx_ws[tok0 + tl] = mi;
            prob_ws[tok0 + tl] = 1.0f / s;
            atomicAdd(&lh[mi], 1);
        }
    }
    __syncthreads();

    // dense logits write: 2048 floats = 4 passes x 128 thr x float4
    const size_t g0 = (size_t)tok0 * NE;
#pragma unroll
    for (int i = 0; i < 4; ++i) {
        const int fl = i * 512 + tid * 4;
        *(float4*)&logits[g0 + fl] = *(const float4*)&sLog[fl];
    }
    if (tid < NE) hist[blockIdx.x * NE + tid] = lh[tid];
}

// ---------------------------------------------------------------------------
// K2: output kernel. One block per 64-token slab (512 blocks x 256 thr):
//   base = sum of this batch's preceding 32-chunk hists (4-wave strided),
//   ordered capacity rank (wave 0, lane = expert, INCLUSIVE <= CAPACITY),
//   dense float4 writes of e_out / p_out (no zero-fill, no RMW).
// ---------------------------------------------------------------------------
__global__ __launch_bounds__(256) void k_out(const int* __restrict__ idx_ws,
                                             const float* __restrict__ prob_ws,
                                             const int* __restrict__ hist,
                                             float* __restrict__ e_out,
                                             float* __restrict__ p_out)
{
    __shared__ int sMi[OCH];
    __shared__ float sPr[OCH];
    __shared__ int sAd[OCH];
    __shared__ int pp[4][NE];

    const int c = blockIdx.x;        // 0..511
    const int b = c >> 7;            // batch (128 slabs per batch)
    const int s = c & 127;           // slab within batch
    const int t0 = c * OCH;
    const int tid = threadIdx.x;
    const int lane = tid & 63;
    const int wv = tid >> 6;

    if (tid < OCH) {
        sMi[tid] = idx_ws[t0 + tid];
        sPr[tid] = prob_ws[t0 + tid];
    }

    // strided partial sums over the batch's preceding 2*s 32-chunks
    {
        int run = 0;
        const int* hrow = hist + (size_t)(b * C32PB) * NE + lane;
        const int n = 2 * s;
        for (int i = wv; i < n; i += 4) run += hrow[i * NE];
        pp[wv][lane] = run;
    }
    __syncthreads();

    if (wv == 0) {
        int run = pp[0][lane] + pp[1][lane] + pp[2][lane] + pp[3][lane];
        for (int j = 0; j < OCH; ++j) {
            if (sMi[j] == lane) { ++run; sAd[j] = (run <= CAPACITY) ? 1 : 0; }
        }
    }
    __syncthreads();

    // dense e/p writes: 4096 floats each = 4 passes x 256 thr x float4
    const size_t g0 = (size_t)t0 * NE;
#pragma unroll
    for (int i = 0; i < 4; ++i) {
        const int fl = i * 1024 + tid * 4;
        const int t = fl >> 6;
        const int e0 = fl & 63;
        const int mi = sMi[t];
        const float pr = sPr[t];
        const int ad = sAd[t];
        float4 ev, pv;
        float* evp = &ev.x;
        float* pvp = &pv.x;
#pragma unroll
        for (int cc = 0; cc < 4; ++cc) {
            const bool hit = (mi == e0 + cc) && ad;
            evp[cc] = hit ? 1.0f : 0.0f;
            pvp[cc] = hit ? pr : 0.0f;
        }
        *(float4*)&e_out[g0 + fl] = ev;
        *(float4*)&p_out[g0 + fl] = pv;
    }
}

// ---------------------------------------------------------------------------
extern "C" void kernel_launch(void* const* d_in, const int* in_sizes, int n_in,
                              void* d_out, int out_size, void* d_ws, size_t ws_size,
                              hipStream_t stream)
{
    const float* x = (const float*)d_in[0];   // [B,S,D] fp32
    const float* W = (const float*)d_in[1];   // [E,D] fp32
    // d_in[2] = top_k (==1), ignored

    float* out = (float*)d_out;
    float* e_out = out;                          // expert_indices as 0.0/1.0
    float* p_out = out + (size_t)NM * NE;        // router_probs
    float* logits = out + 2 * (size_t)NM * NE;   // logits

    char* ws = (char*)d_ws;
    int* idx_ws    = (int*)ws;                                   // 128 KB
    float* prob_ws = (float*)(ws + (size_t)NM * 4);              // 128 KB
    int* hist      = (int*)(ws + (size_t)NM * 8);                // 1024*64*4 = 256 KB
    unsigned short* Wh = (unsigned short*)(ws + (size_t)NM * 8 + (size_t)NBLK * NE * 4);
    unsigned short* Wl = Wh + (size_t)NE * ND;                   // 128 KB each

    w_conv<<<NE * ND / (256 * 4), 256, 0, stream>>>(W, Wh, Wl);
    k1_mfma<<<NBLK, 128, 0, stream>>>(x, Wh, Wl, logits, idx_ws, prob_ws, hist);
    k_out<<<NOB, 256, 0, stream>>>(idx_ws, prob_ws, hist, e_out, p_out);
}

// Round 8
// 53.123 us; speedup vs baseline: 1.8879x; 1.0140x over previous
//
#include <hip/hip_runtime.h>
#include <hip/hip_bf16.h>

// Problem constants (fixed by setup_inputs): B=4, S=8192, D=1024, E=64, top_k=1
#define NB 4
#define NS 8192
#define ND 1024
#define NE 64
#define NM (NB * NS)          // 32768 tokens
#define CAPACITY 640

#define BM 32                 // tokens per k1 block (= hist chunk size)
#define BK 64                 // K-tile
#define NKT (ND / BK)         // 16 K-tiles
#define NBLK (NM / BM)        // 1024 blocks -> 4/CU
#define C32PB (NS / BM)       // 256 32-chunks per batch

#define OCH 64                // tokens per output block
#define NOB (NM / OCH)        // 512 output blocks

typedef short short8 __attribute__((ext_vector_type(8)));
typedef unsigned short ushort8 __attribute__((ext_vector_type(8)));
typedef float f32x4 __attribute__((ext_vector_type(4)));

// LDS swizzle: flat short-index within a [rows][64 shorts] tile.
// XOR bits 3-5 of the column with (row&7): conflict-free b128 column reads.
__device__ __forceinline__ int swz(int row, int colshorts) {
    return row * 64 + (colshorts ^ ((row & 7) << 3));
}

// ---------------------------------------------------------------------------
// K0: split W (fp32 [E][D]) into bf16 hi/lo planes (RNE both levels).
// ---------------------------------------------------------------------------
__global__ __launch_bounds__(256) void w_conv(const float* __restrict__ W,
                                              unsigned short* __restrict__ Wh,
                                              unsigned short* __restrict__ Wl)
{
    const int i = (blockIdx.x * 256 + threadIdx.x) * 4;
    float4 v = *(const float4*)(W + i);
    float f[4] = {v.x, v.y, v.z, v.w};
    ushort4 h, l;
    unsigned short* hp = &h.x;
    unsigned short* lp = &l.x;
#pragma unroll
    for (int c = 0; c < 4; ++c) {
        __hip_bfloat16 hb = __float2bfloat16(f[c]);
        float r = f[c] - __bfloat162float(hb);
        __hip_bfloat16 lb = __float2bfloat16(r);
        hp[c] = __builtin_bit_cast(unsigned short, hb);
        lp[c] = __builtin_bit_cast(unsigned short, lb);
    }
    *(ushort4*)(Wh + i) = h;
    *(ushort4*)(Wl + i) = l;
}

// ---------------------------------------------------------------------------
// K1: LDS-tiled bf16x3-split MFMA GEMM + fused softmax-top1.
// 128 threads = 2 waves; BM=32 tokens x 64 experts, 16 K-tiles of 64.
// FULL register prefetch: tile kt+1's x AND W loads are issued at the top of
// tile kt and stay in flight across the barrier + MFMA phase. Staging writes
// come from registers only. __launch_bounds__(128,2) -> VGPR cap 256 so the
// compiler cannot sink the prefetch (r7 post-mortem: 56 VGPRs = dead pipeline).
// MFMA sequence bitwise-identical to r5/r6/r7 (same logits, same argmax).
// C/D layout (verified m89/m91): col = lane&15 (expert), row = (lane>>4)*4+reg.
// ---------------------------------------------------------------------------
__global__ __launch_bounds__(128, 2) void k1_mfma(const float* __restrict__ x,
                                                  const unsigned short* __restrict__ Wh,
                                                  const unsigned short* __restrict__ Wl,
                                                  float* __restrict__ logits,
                                                  int* __restrict__ idx_ws,
                                                  float* __restrict__ prob_ws,
                                                  int* __restrict__ hist)
{
    __shared__ char sbuf[8192];       // xs_h(4K)+xs_l(4K); reused as sLog (2048 f32)
    __shared__ short whs[64 * 64];    // 8 KB
    __shared__ short wls[64 * 64];    // 8 KB
    __shared__ int lh[NE];

    short* xs_h = (short*)sbuf;
    short* xs_l = (short*)(sbuf + 4096);
    float* sLog = (float*)sbuf;

    const int tid = threadIdx.x;
    const int lane = tid & 63;
    const int wv = tid >> 6;          // 0..1
    const int lr = lane & 15;
    const int kq = lane >> 4;
    const int tok0 = blockIdx.x * BM;

    if (tid < NE) lh[tid] = 0;

    // x staging coords: row = tid>>2 (0..31), col group = (tid&3)*16
    const int xrow = tid >> 2;
    const int xcol = (tid & 3) * 16;
    const float* xsrc = x + (size_t)(tok0 + xrow) * ND + xcol;

    // W staging coords: per instr i in 0..3: e = (tid>>3)+i*16, col=(tid&7)*8
    const int we0 = tid >> 3;         // 0..15
    const int wcol = (tid & 7) * 8;

    f32x4 acc[4];
#pragma unroll
    for (int j = 0; j < 4; ++j) acc[j] = (f32x4){0.f, 0.f, 0.f, 0.f};

    // ---- prologue: load tile 0 (x + W planes) into registers
    float4 px[4], px2[4];
    ushort8 pwh[4], pwl[4], pwh2[4], pwl2[4];
#pragma unroll
    for (int c = 0; c < 4; ++c) px[c] = *(const float4*)(xsrc + c * 4);
#pragma unroll
    for (int i = 0; i < 4; ++i) {
        const size_t gs = (size_t)(we0 + i * 16) * ND + wcol;
        pwh[i] = *(const ushort8*)(Wh + gs);
        pwl[i] = *(const ushort8*)(Wl + gs);
    }

#pragma unroll
    for (int kt = 0; kt < NKT; ++kt) {
        const int k0 = kt * BK;
        if (kt > 0) __syncthreads();   // all waves done reading previous tile

        // ---- issue next tile's global loads FIRST (in flight across
        //      the stage writes + barrier + MFMA phase)
        if (kt + 1 < NKT) {
#pragma unroll
            for (int c = 0; c < 4; ++c)
                px2[c] = *(const float4*)(xsrc + (k0 + BK) + c * 4);
#pragma unroll
            for (int i = 0; i < 4; ++i) {
                const size_t gs = (size_t)(we0 + i * 16) * ND + (k0 + BK) + wcol;
                pwh2[i] = *(const ushort8*)(Wh + gs);
                pwl2[i] = *(const ushort8*)(Wl + gs);
            }
        }

        // ---- stage W planes from registers (swizzled ds_write)
#pragma unroll
        for (int i = 0; i < 4; ++i) {
            const int si = swz(we0 + i * 16, wcol);
            *(ushort8*)&whs[si] = pwh[i];
            *(ushort8*)&wls[si] = pwl[i];
        }

        // ---- stage x: trunc-split px -> hi/lo, swizzled ds_write (8 B each)
#pragma unroll
        for (int c = 0; c < 4; ++c) {
            float f[4] = {px[c].x, px[c].y, px[c].z, px[c].w};
            ushort4 h4, l4;
            unsigned short* hp = &h4.x;
            unsigned short* lp = &l4.x;
#pragma unroll
            for (int e = 0; e < 4; ++e) {
                unsigned int u = __builtin_bit_cast(unsigned int, f[e]);
                hp[e] = (unsigned short)(u >> 16);
                float fhi = __builtin_bit_cast(float, u & 0xFFFF0000u);
                lp[e] = (unsigned short)(__builtin_bit_cast(unsigned int, f[e] - fhi) >> 16);
            }
            const int si = swz(xrow, xcol + c * 4);
            *(ushort4*)&xs_h[si] = h4;
            *(ushort4*)&xs_l[si] = l4;
        }

        __syncthreads();   // tile ready

        // ---- fragments + MFMA
#pragma unroll
        for (int kk = 0; kk < 2; ++kk) {
            const int col = kk * 32 + kq * 8;
            const int arow = wv * 16 + lr;
            short8 ah = *(const short8*)&xs_h[swz(arow, col)];
            short8 al = *(const short8*)&xs_l[swz(arow, col)];
#pragma unroll
            for (int j = 0; j < 4; ++j) {
                const int erow = j * 16 + lr;
                short8 bh = *(const short8*)&whs[swz(erow, col)];
                short8 bl = *(const short8*)&wls[swz(erow, col)];
                acc[j] = __builtin_amdgcn_mfma_f32_16x16x32_bf16(ah, bh, acc[j], 0, 0, 0);
                acc[j] = __builtin_amdgcn_mfma_f32_16x16x32_bf16(ah, bl, acc[j], 0, 0, 0);
                acc[j] = __builtin_amdgcn_mfma_f32_16x16x32_bf16(al, bh, acc[j], 0, 0, 0);
            }
        }

        // rotate register buffers (SSA-renamed by the full unroll; no movs)
#pragma unroll
        for (int c = 0; c < 4; ++c) px[c] = px2[c];
#pragma unroll
        for (int i = 0; i < 4; ++i) { pwh[i] = pwh2[i]; pwl[i] = pwl2[i]; }
    }

    __syncthreads();   // xs tiles dead; sLog may now overwrite them

    // ---- fused epilogue: per-token softmax top-1 (each wave: its 16 tokens)
#pragma unroll
    for (int r = 0; r < 4; ++r) {
        const int tl = wv * 16 + kq * 4 + r;   // token local to block (0..31)
        float val[4];
#pragma unroll
        for (int j = 0; j < 4; ++j) val[j] = acc[j][r];

        // local argmax over j (ascending j + strict > keeps lowest expert)
        float m = val[0];
        int mi = lr;
#pragma unroll
        for (int j = 1; j < 4; ++j) {
            if (val[j] > m) { m = val[j]; mi = j * 16 + lr; }
        }
        // butterfly across the 16 lanes of this fragment-row group
#pragma unroll
        for (int off = 1; off < 16; off <<= 1) {
            float m2 = __shfl_xor(m, off);
            int mi2 = __shfl_xor(mi, off);
            if (m2 > m || (m2 == m && mi2 < mi)) { m = m2; mi = mi2; }
        }
        // softmax denominator
        float s = 0.0f;
#pragma unroll
        for (int j = 0; j < 4; ++j) s += __expf(val[j] - m);
#pragma unroll
        for (int off = 1; off < 16; off <<= 1) s += __shfl_xor(s, off);

        // stage logits in LDS for dense write
#pragma unroll
        for (int j = 0; j < 4; ++j) sLog[tl * NE + j * 16 + lr] = val[j];
        if (lr == 0) {
            idx_ws[tok0 + tl] = mi;
            prob_ws[tok0 + tl] = 1.0f / s;
            atomicAdd(&lh[mi], 1);
        }
    }
    __syncthreads();

    // dense logits write: 2048 floats = 4 passes x 128 thr x float4
    const size_t g0 = (size_t)tok0 * NE;
#pragma unroll
    for (int i = 0; i < 4; ++i) {
        const int fl = i * 512 + tid * 4;
        *(float4*)&logits[g0 + fl] = *(const float4*)&sLog[fl];
    }
    if (tid < NE) hist[blockIdx.x * NE + tid] = lh[tid];
}

// ---------------------------------------------------------------------------
// K2: output kernel. One block per 64-token slab (512 blocks x 256 thr):
//   base = sum of this batch's preceding 32-chunk hists (4-wave strided),
//   ordered capacity rank (wave 0, lane = expert, INCLUSIVE <= CAPACITY),
//   dense float4 writes of e_out / p_out (no zero-fill, no RMW).
// ---------------------------------------------------------------------------
__global__ __launch_bounds__(256) void k_out(const int* __restrict__ idx_ws,
                                             const float* __restrict__ prob_ws,
                                             const int* __restrict__ hist,
                                             float* __restrict__ e_out,
                                             float* __restrict__ p_out)
{
    __shared__ int sMi[OCH];
    __shared__ float sPr[OCH];
    __shared__ int sAd[OCH];
    __shared__ int pp[4][NE];

    const int c = blockIdx.x;        // 0..511
    const int b = c >> 7;            // batch (128 slabs per batch)
    const int s = c & 127;           // slab within batch
    const int t0 = c * OCH;
    const int tid = threadIdx.x;
    const int lane = tid & 63;
    const int wv = tid >> 6;

    if (tid < OCH) {
        sMi[tid] = idx_ws[t0 + tid];
        sPr[tid] = prob_ws[t0 + tid];
    }

    // strided partial sums over the batch's preceding 2*s 32-chunks
    {
        int run = 0;
        const int* hrow = hist + (size_t)(b * C32PB) * NE + lane;
        const int n = 2 * s;
        for (int i = wv; i < n; i += 4) run += hrow[i * NE];
        pp[wv][lane] = run;
    }
    __syncthreads();

    if (wv == 0) {
        int run = pp[0][lane] + pp[1][lane] + pp[2][lane] + pp[3][lane];
        for (int j = 0; j < OCH; ++j) {
            if (sMi[j] == lane) { ++run; sAd[j] = (run <= CAPACITY) ? 1 : 0; }
        }
    }
    __syncthreads();

    // dense e/p writes: 4096 floats each = 4 passes x 256 thr x float4
    const size_t g0 = (size_t)t0 * NE;
#pragma unroll
    for (int i = 0; i < 4; ++i) {
        const int fl = i * 1024 + tid * 4;
        const int t = fl >> 6;
        const int e0 = fl & 63;
        const int mi = sMi[t];
        const float pr = sPr[t];
        const int ad = sAd[t];
        float4 ev, pv;
        float* evp = &ev.x;
        float* pvp = &pv.x;
#pragma unroll
        for (int cc = 0; cc < 4; ++cc) {
            const bool hit = (mi == e0 + cc) && ad;
            evp[cc] = hit ? 1.0f : 0.0f;
            pvp[cc] = hit ? pr : 0.0f;
        }
        *(float4*)&e_out[g0 + fl] = ev;
        *(float4*)&p_out[g0 + fl] = pv;
    }
}

// ---------------------------------------------------------------------------
extern "C" void kernel_launch(void* const* d_in, const int* in_sizes, int n_in,
                              void* d_out, int out_size, void* d_ws, size_t ws_size,
                              hipStream_t stream)
{
    const float* x = (const float*)d_in[0];   // [B,S,D] fp32
    const float* W = (const float*)d_in[1];   // [E,D] fp32
    // d_in[2] = top_k (==1), ignored

    float* out = (float*)d_out;
    float* e_out = out;                          // expert_indices as 0.0/1.0
    float* p_out = out + (size_t)NM * NE;        // router_probs
    float* logits = out + 2 * (size_t)NM * NE;   // logits

    char* ws = (char*)d_ws;
    int* idx_ws    = (int*)ws;                                   // 128 KB
    float* prob_ws = (float*)(ws + (size_t)NM * 4);              // 128 KB
    int* hist      = (int*)(ws + (size_t)NM * 8);                // 1024*64*4 = 256 KB
    unsigned short* Wh = (unsigned short*)(ws + (size_t)NM * 8 + (size_t)NBLK * NE * 4);
    unsigned short* Wl = Wh + (size_t)NE * ND;                   // 128 KB each

    w_conv<<<NE * ND / (256 * 4), 256, 0, stream>>>(W, Wh, Wl);
    k1_mfma<<<NBLK, 128, 0, stream>>>(x, Wh, Wl, logits, idx_ws, prob_ws, hist);
    k_out<<<NOB, 256, 0, stream>>>(idx_ws, prob_ws, hist, e_out, p_out);
}

// Round 9
// 47.052 us; speedup vs baseline: 2.1315x; 1.1290x over previous
//
#include <hip/hip_runtime.h>
#include <hip/hip_bf16.h>

// Problem constants (fixed by setup_inputs): B=4, S=8192, D=1024, E=64, top_k=1
#define NB 4
#define NS 8192
#define ND 1024
#define NE 64
#define NM (NB * NS)          // 32768 tokens
#define CAPACITY 640

#define BM 64                 // tokens per k1 block == hist chunk size
#define BK 64                 // K-tile
#define NKT (ND / BK)         // 16 K-tiles
#define NBLK (NM / BM)        // 512 blocks -> 2/CU (LDS-limited), all resident
#define CPB (NS / BM)         // 128 chunks per batch

#define OCH 64                // tokens per output block
#define NOB (NM / OCH)        // 512 output blocks

typedef short short8 __attribute__((ext_vector_type(8)));
typedef float f32x4 __attribute__((ext_vector_type(4)));

#define GLOAD16(g, l)                                                          \
    __builtin_amdgcn_global_load_lds(                                          \
        (const __attribute__((address_space(1))) void*)(g),                    \
        (__attribute__((address_space(3))) void*)(l), 16, 0, 0)

// ---------------------------------------------------------------------------
// K0: split W (fp32 [E][D]) into bf16 hi/lo planes (RNE both levels).
// ---------------------------------------------------------------------------
__global__ __launch_bounds__(256) void w_conv(const float* __restrict__ W,
                                              unsigned short* __restrict__ Wh,
                                              unsigned short* __restrict__ Wl)
{
    const int i = (blockIdx.x * 256 + threadIdx.x) * 4;
    float4 v = *(const float4*)(W + i);
    float f[4] = {v.x, v.y, v.z, v.w};
    ushort4 h, l;
    unsigned short* hp = &h.x;
    unsigned short* lp = &l.x;
#pragma unroll
    for (int c = 0; c < 4; ++c) {
        __hip_bfloat16 hb = __float2bfloat16(f[c]);
        float r = f[c] - __bfloat162float(hb);
        __hip_bfloat16 lb = __float2bfloat16(r);
        hp[c] = __builtin_bit_cast(unsigned short, hb);
        lp[c] = __builtin_bit_cast(unsigned short, lb);
    }
    *(ushort4*)(Wh + i) = h;
    *(ushort4*)(Wl + i) = l;
}

// ---------------------------------------------------------------------------
// K1: async-DMA (global_load_lds) double-buffered bf16x3-split MFMA GEMM
//     + fused softmax-top1 epilogue.
// 256 threads = 4 waves; BM=64 tokens x 64 experts, 16 K-tiles of 64.
// Staging role-split per tile: wave0/1 -> x rows 0-31/32-63 (fp32, 8 KB each),
// wave2 -> Wh tile, wave3 -> Wl tile (8 KB each). 8 gload_lds(16B) per wave.
// LDS dest is linear (HW: base + lane*16); bank swizzle achieved by
// pre-swizzled SOURCE (16B unit ^ row&15 for x, ^ row&7 for W) and the same
// XOR on the ds_read side (rule #21: both sides or neither).
// Loop: stage(kt+1) -> s_waitcnt vmcnt(8) -> raw s_barrier -> compute(kt)
//       -> raw s_barrier. DMA stays in flight across barriers (counted vmcnt,
//       never 0 mid-loop). x hi/lo split moved to read side — split math and
//       MFMA order elementwise-identical to r5-r8 => bitwise-same logits.
// C/D layout (verified m89/m91): col = lane&15 (expert), row = (lane>>4)*4+reg.
// ---------------------------------------------------------------------------
__global__ __launch_bounds__(256, 2) void k1_mfma(const float* __restrict__ x,
                                                  const unsigned short* __restrict__ Wh,
                                                  const unsigned short* __restrict__ Wl,
                                                  float* __restrict__ logits,
                                                  int* __restrict__ idx_ws,
                                                  float* __restrict__ prob_ws,
                                                  int* __restrict__ hist)
{
    // xs0 [0,16K) | xs1 [16K,32K) | wh0 [32K,40K) | wh1 [40K,48K)
    // wl0 [48K,56K) | wl1 [56K,64K).  sLog reuses [0,16K).
    __shared__ char SL[65536];
    __shared__ int lh[NE];
    __shared__ int sMi[BM];
    __shared__ float sPr[BM];

    const int tid = threadIdx.x;
    const int lane = tid & 63;
    const int wv = tid >> 6;          // 0..3
    const int lr = lane & 15;
    const int kq = lane >> 4;
    const int tok0 = blockIdx.x * BM;

    if (tid < NE) lh[tid] = 0;

    f32x4 acc[4];
#pragma unroll
    for (int j = 0; j < 4; ++j) acc[j] = (f32x4){0.f, 0.f, 0.f, 0.f};

    // ---- async staging (role-split by wave); 8 gload_lds(16B) per wave ----
    auto stage = [&](int kt, int b) {
        const int k0 = kt * BK;
        if (wv < 2) {
            // x rows [wv*32, wv*32+32), fp32 [64][16 units of 16B]
            const int r0 = wv * 32 + (lane >> 4);   // + i*4
            const int uslot = lane & 15;
            char* xd = SL + b * 16384 + wv * 8192;  // wave-uniform
#pragma unroll
            for (int i = 0; i < 8; ++i) {
                const int r = r0 + i * 4;
                const int su = uslot ^ (r & 15);    // pre-swizzled source unit
                const float* g = x + (size_t)(tok0 + r) * ND + k0 + su * 4;
                GLOAD16(g, xd + i * 1024);
            }
        } else {
            // W plane tile [64][8 units of 16B]
            const unsigned short* Ws = (wv == 2) ? Wh : Wl;
            char* wd = SL + 32768 + (wv - 2) * 16384 + b * 8192;
            const int r0 = lane >> 3;               // + i*8
            const int su = (lane & 7) ^ (r0 & 7);   // row&7 == r0&7 (i*8%8==0)
#pragma unroll
            for (int i = 0; i < 8; ++i) {
                const unsigned short* g = Ws + (size_t)(i * 8 + r0) * ND + k0 + su * 8;
                GLOAD16(g, wd + i * 1024);
            }
        }
    };

    // ---- compute one K-tile from buffer b ----
    auto compute = [&](int b) {
        const float* xsb = (const float*)(SL + b * 16384);
        const short* whb = (const short*)(SL + 32768 + b * 8192);
        const short* wlb = (const short*)(SL + 49152 + b * 8192);
        const int arow = wv * 16 + lr;
        const int xbase = arow * 64;
#pragma unroll
        for (int kk = 0; kk < 2; ++kk) {
            const int su = kk * 8 + kq * 2;
            f32x4 a0 = *(const f32x4*)&xsb[xbase + ((su)     ^ lr) * 4]; // arow&15==lr
            f32x4 a1 = *(const f32x4*)&xsb[xbase + ((su + 1) ^ lr) * 4];
            float f[8] = {a0[0], a0[1], a0[2], a0[3], a1[0], a1[1], a1[2], a1[3]};
            short8 ah, al;
#pragma unroll
            for (int c = 0; c < 8; ++c) {
                unsigned int u = __builtin_bit_cast(unsigned int, f[c]);
                ah[c] = (short)(u >> 16);                       // trunc hi (as r5-r8)
                float fhi = __builtin_bit_cast(float, u & 0xFFFF0000u);
                __hip_bfloat16 lb = __float2bfloat16(f[c] - fhi); // RNE lo (as r5-r8)
                al[c] = __builtin_bit_cast(short, lb);
            }
            const int ucol = kk * 4 + kq;
#pragma unroll
            for (int j = 0; j < 4; ++j) {
                const int erow = j * 16 + lr;
                const int off = erow * 64 + ((ucol ^ (lr & 7)) * 8); // erow&7==lr&7
                short8 bh = *(const short8*)&whb[off];
                short8 bl = *(const short8*)&wlb[off];
                acc[j] = __builtin_amdgcn_mfma_f32_16x16x32_bf16(ah, bh, acc[j], 0, 0, 0);
                acc[j] = __builtin_amdgcn_mfma_f32_16x16x32_bf16(ah, bl, acc[j], 0, 0, 0);
                acc[j] = __builtin_amdgcn_mfma_f32_16x16x32_bf16(al, bh, acc[j], 0, 0, 0);
            }
        }
    };

    // ---- main loop: counted-vmcnt 2-phase pipeline ----
    stage(0, 0);
#pragma unroll
    for (int kt = 0; kt < NKT; ++kt) {
        const int b = kt & 1;
        if (kt + 1 < NKT) {
            stage(kt + 1, b ^ 1);
            asm volatile("s_waitcnt vmcnt(8)" ::: "memory");   // tile kt done
        } else {
            asm volatile("s_waitcnt vmcnt(0)" ::: "memory");
        }
        __builtin_amdgcn_s_barrier();
        __builtin_amdgcn_sched_barrier(0);
        compute(b);
        __builtin_amdgcn_sched_barrier(0);
        __builtin_amdgcn_s_barrier();          // reads done; kt+2 may overwrite b
    }

    __syncthreads();   // full fence before reusing xs0 region as sLog

    float* sLog = (float*)SL;

    // ---- fused epilogue: per-token softmax top-1 (each wave: its 16 tokens)
#pragma unroll
    for (int r = 0; r < 4; ++r) {
        const int tl = wv * 16 + kq * 4 + r;   // token local to block (0..63)
        float val[4];
#pragma unroll
        for (int j = 0; j < 4; ++j) val[j] = acc[j][r];

        // local argmax over j (ascending j + strict > keeps lowest expert)
        float m = val[0];
        int mi = lr;
#pragma unroll
        for (int j = 1; j < 4; ++j) {
            if (val[j] > m) { m = val[j]; mi = j * 16 + lr; }
        }
        // butterfly across the 16 lanes of this fragment-row group
#pragma unroll
        for (int off = 1; off < 16; off <<= 1) {
            float m2 = __shfl_xor(m, off);
            int mi2 = __shfl_xor(mi, off);
            if (m2 > m || (m2 == m && mi2 < mi)) { m = m2; mi = mi2; }
        }
        // softmax denominator
        float s = 0.0f;
#pragma unroll
        for (int j = 0; j < 4; ++j) s += __expf(val[j] - m);
#pragma unroll
        for (int off = 1; off < 16; off <<= 1) s += __shfl_xor(s, off);

        // stage logits in LDS for dense write
#pragma unroll
        for (int j = 0; j < 4; ++j) sLog[tl * NE + j * 16 + lr] = val[j];
        if (lr == 0) {
            sMi[tl] = mi;
            idx_ws[tok0 + tl] = mi;
            prob_ws[tok0 + tl] = 1.0f / s;
            atomicAdd(&lh[mi], 1);
        }
    }
    __syncthreads();

    // dense logits write: 4096 floats = 4 passes x 256 thr x float4
    const size_t g0 = (size_t)tok0 * NE;
#pragma unroll
    for (int i = 0; i < 4; ++i) {
        const int fl = i * 1024 + tid * 4;
        *(float4*)&logits[g0 + fl] = *(const float4*)&sLog[fl];
    }
    if (tid < NE) hist[blockIdx.x * NE + tid] = lh[tid];
    (void)sMi; (void)sPr;
}

// ---------------------------------------------------------------------------
// K2: output kernel. One block per 64-token chunk (512 blocks x 256 thr):
//   base = sum of this batch's preceding chunk hists (4-wave strided),
//   ordered capacity rank (wave 0, lane = expert, INCLUSIVE <= CAPACITY),
//   dense float4 writes of e_out / p_out (no zero-fill, no RMW).
// ---------------------------------------------------------------------------
__global__ __launch_bounds__(256) void k_out(const int* __restrict__ idx_ws,
                                             const float* __restrict__ prob_ws,
                                             const int* __restrict__ hist,
                                             float* __restrict__ e_out,
                                             float* __restrict__ p_out)
{
    __shared__ int sMi[OCH];
    __shared__ float sPr[OCH];
    __shared__ int sAd[OCH];
    __shared__ int pp[4][NE];

    const int c = blockIdx.x;        // 0..511 == chunk id
    const int b = c >> 7;            // batch (128 chunks per batch)
    const int s = c & 127;           // chunk within batch
    const int t0 = c * OCH;
    const int tid = threadIdx.x;
    const int lane = tid & 63;
    const int wv = tid >> 6;

    if (tid < OCH) {
        sMi[tid] = idx_ws[t0 + tid];
        sPr[tid] = prob_ws[t0 + tid];
    }

    // strided partial sums over the batch's preceding s chunks
    {
        int run = 0;
        const int* hrow = hist + (size_t)(b * CPB) * NE + lane;
        for (int i = wv; i < s; i += 4) run += hrow[i * NE];
        pp[wv][lane] = run;
    }
    __syncthreads();

    if (wv == 0) {
        int run = pp[0][lane] + pp[1][lane] + pp[2][lane] + pp[3][lane];
        for (int j = 0; j < OCH; ++j) {
            if (sMi[j] == lane) { ++run; sAd[j] = (run <= CAPACITY) ? 1 : 0; }
        }
    }
    __syncthreads();

    // dense e/p writes: 4096 floats each = 4 passes x 256 thr x float4
    const size_t g0 = (size_t)t0 * NE;
#pragma unroll
    for (int i = 0; i < 4; ++i) {
        const int fl = i * 1024 + tid * 4;
        const int t = fl >> 6;
        const int e0 = fl & 63;
        const int mi = sMi[t];
        const float pr = sPr[t];
        const int ad = sAd[t];
        float4 ev, pv;
        float* evp = &ev.x;
        float* pvp = &pv.x;
#pragma unroll
        for (int cc = 0; cc < 4; ++cc) {
            const bool hit = (mi == e0 + cc) && ad;
            evp[cc] = hit ? 1.0f : 0.0f;
            pvp[cc] = hit ? pr : 0.0f;
        }
        *(float4*)&e_out[g0 + fl] = ev;
        *(float4*)&p_out[g0 + fl] = pv;
    }
}

// ---------------------------------------------------------------------------
extern "C" void kernel_launch(void* const* d_in, const int* in_sizes, int n_in,
                              void* d_out, int out_size, void* d_ws, size_t ws_size,
                              hipStream_t stream)
{
    const float* x = (const float*)d_in[0];   // [B,S,D] fp32
    const float* W = (const float*)d_in[1];   // [E,D] fp32
    // d_in[2] = top_k (==1), ignored

    float* out = (float*)d_out;
    float* e_out = out;                          // expert_indices as 0.0/1.0
    float* p_out = out + (size_t)NM * NE;        // router_probs
    float* logits = out + 2 * (size_t)NM * NE;   // logits

    char* ws = (char*)d_ws;
    int* idx_ws    = (int*)ws;                                   // 128 KB
    float* prob_ws = (float*)(ws + (size_t)NM * 4);              // 128 KB
    int* hist      = (int*)(ws + (size_t)NM * 8);                // 512*64*4 = 128 KB
    unsigned short* Wh = (unsigned short*)(ws + (size_t)NM * 8 + (size_t)NBLK * NE * 4);
    unsigned short* Wl = Wh + (size_t)NE * ND;                   // 128 KB each

    w_conv<<<NE * ND / (256 * 4), 256, 0, stream>>>(W, Wh, Wl);
    k1_mfma<<<NBLK, 256, 0, stream>>>(x, Wh, Wl, logits, idx_ws, prob_ws, hist);
    k_out<<<NOB, 256, 0, stream>>>(idx_ws, prob_ws, hist, e_out, p_out);
}

// Round 10
// 47.010 us; speedup vs baseline: 2.1334x; 1.0009x over previous
//
#include <hip/hip_runtime.h>
#include <hip/hip_bf16.h>

// Problem constants (fixed by setup_inputs): B=4, S=8192, D=1024, E=64, top_k=1
#define NB 4
#define NS 8192
#define ND 1024
#define NE 64
#define NM (NB * NS)          // 32768 tokens
#define CAPACITY 640

#define BM 64                 // tokens per k1 block == hist chunk size
#define BK 64                 // K-tile
#define NKT (ND / BK)         // 16 K-tiles
#define NBLK (NM / BM)        // 512 blocks -> 2/CU (LDS-limited), all resident
#define CPB (NS / BM)         // 128 chunks per batch

#define OCH 64                // tokens per output block
#define NOB (NM / OCH)        // 512 output blocks

typedef short short8 __attribute__((ext_vector_type(8)));
typedef float f32x4 __attribute__((ext_vector_type(4)));

#define GLOAD16(g, l)                                                          \
    __builtin_amdgcn_global_load_lds(                                          \
        (const __attribute__((address_space(1))) void*)(g),                    \
        (__attribute__((address_space(3))) void*)(l), 16, 0, 0)

// ---------------------------------------------------------------------------
// K1: async-DMA (global_load_lds) double-buffered bf16x3-split MFMA GEMM
//     + fused softmax-top1 epilogue.  (r9 structure; W now staged as RAW FP32
//     and split to bf16 hi/lo on the READ side with math identical to the old
//     w_conv pre-pass -> bitwise-identical logits, one fewer kernel.)
// 256 threads = 4 waves; BM=64 tokens x 64 experts, 16 K-tiles of 64.
// Staging role-split per tile (8 gload_lds(16B) per wave):
//   wave0/1 -> x rows 0-31/32-63 (fp32, 8 KB each)
//   wave2/3 -> W rows 0-31/32-63 (fp32, 8 KB each)
// Both tiles land row-linear [64][64] f32 with the 16B-unit XOR swizzle
// (unit ^ row&15) applied on the SOURCE address and undone on the ds_read
// side (rule #21). Loop: stage(kt+1) -> s_waitcnt vmcnt(8) (counted, never 0
// mid-loop) -> raw s_barrier -> compute(kt) -> raw s_barrier.
// C/D layout (verified m89/m91): col = lane&15 (expert), row = (lane>>4)*4+reg.
// ---------------------------------------------------------------------------
__global__ __launch_bounds__(256, 2) void k1_mfma(const float* __restrict__ x,
                                                  const float* __restrict__ W,
                                                  float* __restrict__ logits,
                                                  int* __restrict__ idx_ws,
                                                  float* __restrict__ prob_ws,
                                                  int* __restrict__ hist)
{
    // xs0 [0,16K) | xs1 [16K,32K) | ws0 [32K,48K) | ws1 [48K,64K)
    // sLog reuses [0,16K).
    __shared__ char SL[65536];
    __shared__ int lh[NE];

    const int tid = threadIdx.x;
    const int lane = tid & 63;
    const int wv = tid >> 6;          // 0..3
    const int lr = lane & 15;
    const int kq = lane >> 4;
    const int tok0 = blockIdx.x * BM;

    if (tid < NE) lh[tid] = 0;

    f32x4 acc[4];
#pragma unroll
    for (int j = 0; j < 4; ++j) acc[j] = (f32x4){0.f, 0.f, 0.f, 0.f};

    // ---- async staging (role-split by wave); 8 gload_lds(16B) per wave ----
    auto stage = [&](int kt, int b) {
        const int k0 = kt * BK;
        const int half = wv & 1;                    // row half 0/1
        const int r0 = half * 32 + (lane >> 4);     // + i*4
        const int uslot = lane & 15;
        const float* src;
        char* dst;
        if (wv < 2) {
            src = x + (size_t)(tok0)*ND;
            dst = SL + b * 16384 + half * 8192;
        } else {
            src = W;
            dst = SL + 32768 + b * 16384 + half * 8192;
        }
#pragma unroll
        for (int i = 0; i < 8; ++i) {
            const int r = r0 + i * 4;
            const int su = uslot ^ (r & 15);        // pre-swizzled source unit
            const float* g = src + (size_t)r * ND + k0 + su * 4;
            GLOAD16(g, dst + i * 1024);
        }
    };

    // ---- compute one K-tile from buffer b ----
    auto compute = [&](int b) {
        const float* xsb = (const float*)(SL + b * 16384);
        const float* wsb = (const float*)(SL + 32768 + b * 16384);
        const int arow = wv * 16 + lr;
#pragma unroll
        for (int kk = 0; kk < 2; ++kk) {
            const int su = kk * 8 + kq * 2;
            f32x4 a0 = *(const f32x4*)&xsb[arow * 64 + ((su)     ^ lr) * 4]; // arow&15==lr
            f32x4 a1 = *(const f32x4*)&xsb[arow * 64 + ((su + 1) ^ lr) * 4];
            float f[8] = {a0[0], a0[1], a0[2], a0[3], a1[0], a1[1], a1[2], a1[3]};
            short8 ah, al;
#pragma unroll
            for (int c = 0; c < 8; ++c) {
                unsigned int u = __builtin_bit_cast(unsigned int, f[c]);
                ah[c] = (short)(u >> 16);                         // trunc hi (as r5-r9)
                float fhi = __builtin_bit_cast(float, u & 0xFFFF0000u);
                __hip_bfloat16 lb = __float2bfloat16(f[c] - fhi); // RNE lo (as r5-r9)
                al[c] = __builtin_bit_cast(short, lb);
            }
#pragma unroll
            for (int j = 0; j < 4; ++j) {
                const int erow = j * 16 + lr;                     // erow&15 == lr
                f32x4 w0 = *(const f32x4*)&wsb[erow * 64 + ((su)     ^ lr) * 4];
                f32x4 w1 = *(const f32x4*)&wsb[erow * 64 + ((su + 1) ^ lr) * 4];
                float g[8] = {w0[0], w0[1], w0[2], w0[3], w1[0], w1[1], w1[2], w1[3]};
                short8 bh, bl;
#pragma unroll
                for (int c = 0; c < 8; ++c) {
                    __hip_bfloat16 hb = __float2bfloat16(g[c]);   // RNE hi (== w_conv)
                    float r = g[c] - __bfloat162float(hb);
                    __hip_bfloat16 lb = __float2bfloat16(r);      // RNE lo (== w_conv)
                    bh[c] = __builtin_bit_cast(short, hb);
                    bl[c] = __builtin_bit_cast(short, lb);
                }
                acc[j] = __builtin_amdgcn_mfma_f32_16x16x32_bf16(ah, bh, acc[j], 0, 0, 0);
                acc[j] = __builtin_amdgcn_mfma_f32_16x16x32_bf16(ah, bl, acc[j], 0, 0, 0);
                acc[j] = __builtin_amdgcn_mfma_f32_16x16x32_bf16(al, bh, acc[j], 0, 0, 0);
            }
        }
    };

    // ---- main loop: counted-vmcnt 2-phase pipeline ----
    stage(0, 0);
#pragma unroll
    for (int kt = 0; kt < NKT; ++kt) {
        const int b = kt & 1;
        if (kt + 1 < NKT) {
            stage(kt + 1, b ^ 1);
            asm volatile("s_waitcnt vmcnt(8)" ::: "memory");   // tile kt done
        } else {
            asm volatile("s_waitcnt vmcnt(0)" ::: "memory");
        }
        __builtin_amdgcn_s_barrier();
        __builtin_amdgcn_sched_barrier(0);
        compute(b);
        __builtin_amdgcn_sched_barrier(0);
        __builtin_amdgcn_s_barrier();          // reads done; kt+2 may overwrite b
    }

    __syncthreads();   // full fence before reusing xs0 region as sLog

    float* sLog = (float*)SL;

    // ---- fused epilogue: per-token softmax top-1 (each wave: its 16 tokens)
#pragma unroll
    for (int r = 0; r < 4; ++r) {
        const int tl = wv * 16 + kq * 4 + r;   // token local to block (0..63)
        float val[4];
#pragma unroll
        for (int j = 0; j < 4; ++j) val[j] = acc[j][r];

        // local argmax over j (ascending j + strict > keeps lowest expert)
        float m = val[0];
        int mi = lr;
#pragma unroll
        for (int j = 1; j < 4; ++j) {
            if (val[j] > m) { m = val[j]; mi = j * 16 + lr; }
        }
        // butterfly across the 16 lanes of this fragment-row group
#pragma unroll
        for (int off = 1; off < 16; off <<= 1) {
            float m2 = __shfl_xor(m, off);
            int mi2 = __shfl_xor(mi, off);
            if (m2 > m || (m2 == m && mi2 < mi)) { m = m2; mi = mi2; }
        }
        // softmax denominator
        float s = 0.0f;
#pragma unroll
        for (int j = 0; j < 4; ++j) s += __expf(val[j] - m);
#pragma unroll
        for (int off = 1; off < 16; off <<= 1) s += __shfl_xor(s, off);

        // stage logits in LDS for dense write
#pragma unroll
        for (int j = 0; j < 4; ++j) sLog[tl * NE + j * 16 + lr] = val[j];
        if (lr == 0) {
            idx_ws[tok0 + tl] = mi;
            prob_ws[tok0 + tl] = 1.0f / s;
            atomicAdd(&lh[mi], 1);
        }
    }
    __syncthreads();

    // dense logits write: 4096 floats = 4 passes x 256 thr x float4
    const size_t g0 = (size_t)tok0 * NE;
#pragma unroll
    for (int i = 0; i < 4; ++i) {
        const int fl = i * 1024 + tid * 4;
        *(float4*)&logits[g0 + fl] = *(const float4*)&sLog[fl];
    }
    if (tid < NE) hist[blockIdx.x * NE + tid] = lh[tid];
}

// ---------------------------------------------------------------------------
// K2: output kernel. One block per 64-token chunk (512 blocks x 256 thr):
//   base = sum of this batch's preceding chunk hists (4-wave strided),
//   ordered capacity rank (wave 0, lane = expert, INCLUSIVE <= CAPACITY),
//   dense float4 writes of e_out / p_out (no zero-fill, no RMW).
// ---------------------------------------------------------------------------
__global__ __launch_bounds__(256) void k_out(const int* __restrict__ idx_ws,
                                             const float* __restrict__ prob_ws,
                                             const int* __restrict__ hist,
                                             float* __restrict__ e_out,
                                             float* __restrict__ p_out)
{
    __shared__ int sMi[OCH];
    __shared__ float sPr[OCH];
    __shared__ int sAd[OCH];
    __shared__ int pp[4][NE];

    const int c = blockIdx.x;        // 0..511 == chunk id
    const int b = c >> 7;            // batch (128 chunks per batch)
    const int s = c & 127;           // chunk within batch
    const int t0 = c * OCH;
    const int tid = threadIdx.x;
    const int lane = tid & 63;
    const int wv = tid >> 6;

    if (tid < OCH) {
        sMi[tid] = idx_ws[t0 + tid];
        sPr[tid] = prob_ws[t0 + tid];
    }

    // strided partial sums over the batch's preceding s chunks
    {
        int run = 0;
        const int* hrow = hist + (size_t)(b * CPB) * NE + lane;
        for (int i = wv; i < s; i += 4) run += hrow[i * NE];
        pp[wv][lane] = run;
    }
    __syncthreads();

    if (wv == 0) {
        int run = pp[0][lane] + pp[1][lane] + pp[2][lane] + pp[3][lane];
        for (int j = 0; j < OCH; ++j) {
            if (sMi[j] == lane) { ++run; sAd[j] = (run <= CAPACITY) ? 1 : 0; }
        }
    }
    __syncthreads();

    // dense e/p writes: 4096 floats each = 4 passes x 256 thr x float4
    const size_t g0 = (size_t)t0 * NE;
#pragma unroll
    for (int i = 0; i < 4; ++i) {
        const int fl = i * 1024 + tid * 4;
        const int t = fl >> 6;
        const int e0 = fl & 63;
        const int mi = sMi[t];
        const float pr = sPr[t];
        const int ad = sAd[t];
        float4 ev, pv;
        float* evp = &ev.x;
        float* pvp = &pv.x;
#pragma unroll
        for (int cc = 0; cc < 4; ++cc) {
            const bool hit = (mi == e0 + cc) && ad;
            evp[cc] = hit ? 1.0f : 0.0f;
            pvp[cc] = hit ? pr : 0.0f;
        }
        *(float4*)&e_out[g0 + fl] = ev;
        *(float4*)&p_out[g0 + fl] = pv;
    }
}

// ---------------------------------------------------------------------------
extern "C" void kernel_launch(void* const* d_in, const int* in_sizes, int n_in,
                              void* d_out, int out_size, void* d_ws, size_t ws_size,
                              hipStream_t stream)
{
    const float* x = (const float*)d_in[0];   // [B,S,D] fp32
    const float* W = (const float*)d_in[1];   // [E,D] fp32
    // d_in[2] = top_k (==1), ignored

    float* out = (float*)d_out;
    float* e_out = out;                          // expert_indices as 0.0/1.0
    float* p_out = out + (size_t)NM * NE;        // router_probs
    float* logits = out + 2 * (size_t)NM * NE;   // logits

    char* ws = (char*)d_ws;
    int* idx_ws    = (int*)ws;                                   // 128 KB
    float* prob_ws = (float*)(ws + (size_t)NM * 4);              // 128 KB
    int* hist      = (int*)(ws + (size_t)NM * 8);                // 512*64*4 = 128 KB

    k1_mfma<<<NBLK, 256, 0, stream>>>(x, W, logits, idx_ws, prob_ws, hist);
    k_out<<<NOB, 256, 0, stream>>>(idx_ws, prob_ws, hist, e_out, p_out);
}